// Round 8
// baseline (63.959 us; speedup 1.0000x reference)
//
#include <hip/hip_runtime.h>

// ConvCapsules2d:
//  activations: [8,32,14,14] f32
//  poses:       [8,32,4,4,14,14] f32   (n,b,i,m,h,w)
//  W_ij:        [32,32,4,4,3,3] f32    (b,c,m,j,k,l)
// Outputs (concatenated flat):
//  acts_out: [8,32,6,6,3,3]                  = 82944 f32
//  V_ji:     [8,32,32,16,6,6,3,3]            = 42467328 f32
// V[n,b,c,i,j,f,g,k,l] = sum_m poses[n,b,i,m,f*2+k,g*2+l] * W[b,c,m,j,k,l]
// r = f*54 + g*9 + k*3 + l ; wo(r) = r%9 ; po(r) = (f*2+k)*14 + (g*2+l)
//
// v7: lanes along the FLAT output index -> every wave-store is one contiguous
// 1024B, 256B-aligned, line-complete burst (no split cache lines / RMW).

#define RLEN 324
#define ACTS_OUT 82944
#define PSTRIDE 20          // padded row stride in dwords (16 data + 4 pad)
#define CPB 8               // c's per block
#define UNITS (CPB * 1296)  // dwordx4 units per block (1296 = 16*324/4)

__device__ __forceinline__ int po_of(int r) {
    int f = r / 54;  int r1 = r - f * 54;
    int g = r1 / 9;  int r2 = r1 - g * 9;
    int k = r2 / 3;  int l  = r2 - k * 3;
    return (f * 2 + k) * 14 + (g * 2 + l);
}

// grid = 1024: bid = nb*4 + ch ; block covers c = ch*8 + cl, cl in [0,8)
__global__ __launch_bounds__(256, 4) void v7_kernel(const float* __restrict__ act,
                                                    const float* __restrict__ poses,
                                                    const float* __restrict__ W,
                                                    float* __restrict__ out) {
    __shared__ float    Pl[196 * PSTRIDE];      // [po][i*4+m], 15.7 KB
    __shared__ float    Wl[CPB][9 * PSTRIDE];   // [cl][wo][j*4+m], 5.8 KB
    __shared__ unsigned tbl[RLEN];              // po | wo<<16

    const int bid = blockIdx.x;
    const int nb  = bid >> 2;            // n*32 + b
    const int ch  = bid & 3;
    const int b   = nb & 31;
    const int tid = threadIdx.x;

    // ---- stage poses[n,b] transposed: Pl[po*20 + i*4+m] = poses[nb][i][m][po]
    const float* pn = poses + (size_t)nb * 3136;
    for (int t = tid; t < 784; t += 256) {
        int i  = t / 196;
        int po = t - i * 196;
        float4 v;
        v.x = pn[(i * 4 + 0) * 196 + po];
        v.y = pn[(i * 4 + 1) * 196 + po];
        v.z = pn[(i * 4 + 2) * 196 + po];
        v.w = pn[(i * 4 + 3) * 196 + po];
        *(float4*)&Pl[po * PSTRIDE + i * 4] = v;
    }
    // ---- stage W: Wl[cl][wo*20 + j*4+m] = W[b, ch*8+cl][m][j][wo]
    for (int t = tid; t < CPB * 36; t += 256) {
        int cl = t / 36;
        int s  = t - cl * 36;
        int wo = s / 4, j = s & 3;
        const float* wb = W + ((size_t)(b * 32 + ch * CPB + cl)) * 144 + j * 9 + wo;
        float4 v;                       // over m: stride 36
        v.x = wb[0];  v.y = wb[36];  v.z = wb[72];  v.w = wb[108];
        *(float4*)&Wl[cl][wo * PSTRIDE + j * 4] = v;
    }
    // ---- packed (po, wo) table
    for (int r = tid; r < RLEN; r += 256)
        tbl[r] = (unsigned)po_of(r) | ((unsigned)(r % 9) << 16);
    __syncthreads();

    // ---- fused acts_out gather (ch==0 blocks only)
    if (ch == 0) {
        const float* an = act + (size_t)nb * 196;
        for (int a = tid; a < RLEN; a += 256)
            out[nb * RLEN + a] = an[tbl[a] & 0xffffu];
    }

    // ---- main loop: one dwordx4 unit per item (4 consecutive r, fixed c,ij)
    // block output = ONE contiguous span: out + ACTS_OUT + (nb*32+ch*8)*5184
    float* obase = out + ACTS_OUT + ((size_t)(nb * 32 + ch * CPB)) * 5184;
    const float* Wf = &Wl[0][0];
    for (int item = tid; item < UNITS; item += 256) {
        int cl = item / 1296;
        int u  = item - cl * 1296;       // ij*81 + q
        int ij = u / 81;
        int q  = u - ij * 81;
        int i  = ij >> 2, j = ij & 3;

        uint4 pk = *(const uint4*)&tbl[q * 4];   // r = 4q+e
        const float* Wb = Wf + cl * (9 * PSTRIDE);

        float o[4];
        #pragma unroll
        for (int e = 0; e < 4; ++e) {
            unsigned pe = (e == 0) ? pk.x : (e == 1) ? pk.y : (e == 2) ? pk.z : pk.w;
            int po = (int)(pe & 0xffffu);
            int wo = (int)(pe >> 16);
            float4 p = *(const float4*)&Pl[po * PSTRIDE + i * 4];   // m0..3
            float4 w = *(const float4*)&Wb[wo * PSTRIDE + j * 4];   // m0..3
            o[e] = p.x * w.x + p.y * w.y + p.z * w.z + p.w * w.w;
        }
        // lanes = consecutive item -> contiguous 1024B, 256B-aligned burst
        *(float4*)&obase[(size_t)item * 4] = make_float4(o[0], o[1], o[2], o[3]);
    }
}

extern "C" void kernel_launch(void* const* d_in, const int* in_sizes, int n_in,
                              void* d_out, int out_size, void* d_ws, size_t ws_size,
                              hipStream_t stream) {
    const float* act   = (const float*)d_in[0];
    const float* poses = (const float*)d_in[1];
    const float* W     = (const float*)d_in[2];
    float* out = (float*)d_out;

    v7_kernel<<<1024, 256, 0, stream>>>(act, poses, W, out);
}

// Round 9
// 34.146 us; speedup vs baseline: 1.8731x; 1.8731x over previous
//
#include <hip/hip_runtime.h>

// ConvCapsules2d:
//  activations: [8,32,14,14] f32
//  poses:       [8,32,4,4,14,14] f32   (n,b,i,m,h,w)
//  W_ij:        [32,32,4,4,3,3] f32    (b,c,m,j,k,l)
// Outputs (concatenated flat):
//  acts_out: [8,32,6,6,3,3]                  = 82944 f32
//  V_ji:     [8,32,32,16,6,6,3,3]            = 42467328 f32
// V[n,b,c,i,j,f,g,k,l] = sum_m poses[n,b,i,m,f*2+k,g*2+l] * W[b,c,m,j,k,l]
// r = f*54 + g*9 + k*3 + l ; wo(r) = r%9 ; po(r) = (f*2+k)*14 + (g*2+l)
//
// v8 == v5 structure (CPB=8, grid 1024, 256 thr) with PLAIN stores
// (v5's regression hypothesis: __builtin_nontemporal_store bypassed L2
//  write-combining -> ~2.2x write-path loss).

#define RLEN 324
#define ACTS_OUT 82944
#define PSTRIDE 20          // dwords per padded row (16 data + 4 pad)
#define CPB 8               // c's per block
#define ITEMS (CPB * RLEN)  // 2592 work items per block

__device__ __forceinline__ int po_of(int r) {
    int f = r / 54;  int r1 = r - f * 54;
    int g = r1 / 9;  int r2 = r1 - g * 9;
    int k = r2 / 3;  int l  = r2 - k * 3;
    return (f * 2 + k) * 14 + (g * 2 + l);
}

// grid = 1024: bid = nb*4 + cq ; block covers c = cq*8 .. cq*8+7
__global__ __launch_bounds__(256, 4) void v8_kernel(const float* __restrict__ act,
                                                    const float* __restrict__ poses,
                                                    const float* __restrict__ W,
                                                    float* __restrict__ out) {
    __shared__ float Pl2[196 * PSTRIDE];        // Pl2[po][i*4+m], 15.7 KB
    __shared__ float Wall[CPB][9 * PSTRIDE];    // Wall[cl][wo][m*4+j], 5.8 KB

    const int bid = blockIdx.x;
    const int nb  = bid >> 2;                   // n*32 + b
    const int cq  = bid & 3;
    const int b   = nb & 31;
    const int tid = threadIdx.x;

    // ---- stage poses[n,b] transposed (once per block)
    const float* pn = poses + (size_t)nb * 3136;
    for (int t = tid; t < 784; t += 256) {
        int i  = t / 196;
        int po = t - i * 196;
        float4 v;
        v.x = pn[(i * 4 + 0) * 196 + po];
        v.y = pn[(i * 4 + 1) * 196 + po];
        v.z = pn[(i * 4 + 2) * 196 + po];
        v.w = pn[(i * 4 + 3) * 196 + po];
        *(float4*)&Pl2[po * PSTRIDE + i * 4] = v;
    }
    // ---- stage W[b, cq*8 .. cq*8+7] transposed: Wall[cl][wo][m*4+j]
    for (int t = tid; t < CPB * 36; t += 256) {
        int cl = t / 36;
        int s  = t - cl * 36;
        int wo = s >> 2, m = s & 3;
        const float* wb = W + ((size_t)(b * 32 + cq * CPB + cl)) * 144 + m * 36 + wo;
        float4 v;
        v.x = wb[0 * 9];
        v.y = wb[1 * 9];
        v.z = wb[2 * 9];
        v.w = wb[3 * 9];
        *(float4*)&Wall[cl][wo * PSTRIDE + m * 4] = v;
    }
    __syncthreads();

    // ---- fused acts_out gather (only cq==0 blocks)
    if (cq == 0) {
        const float* an = act + (size_t)nb * 196;
        for (int a = tid; a < RLEN; a += 256)
            out[nb * RLEN + a] = an[po_of(a)];
    }

    // ---- main compute/store loop: 16 outputs per item
    for (int item = tid; item < ITEMS; item += 256) {
        unsigned cl = (unsigned)item / RLEN;
        int r  = item - (int)cl * RLEN;
        int po = po_of(r);
        int wo = r % 9;

        const float* Pb = &Pl2[po * PSTRIDE];
        const float* Wb = &Wall[cl][wo * PSTRIDE];
        float4 p0 = *(const float4*)&Pb[0];     // i=0: m0..3
        float4 p1 = *(const float4*)&Pb[4];
        float4 p2 = *(const float4*)&Pb[8];
        float4 p3 = *(const float4*)&Pb[12];
        float4 w0 = *(const float4*)&Wb[0];     // m=0: j0..3
        float4 w1 = *(const float4*)&Wb[4];
        float4 w2 = *(const float4*)&Wb[8];
        float4 w3 = *(const float4*)&Wb[12];

        int c = cq * CPB + (int)cl;
        float* obase = out + ACTS_OUT + ((size_t)(nb * 32 + c)) * 5184 + r;
        #pragma unroll
        for (int i = 0; i < 4; ++i) {
            float4 pi = (i == 0) ? p0 : (i == 1) ? p1 : (i == 2) ? p2 : p3;
            float4 v;
            v.x = pi.x * w0.x + pi.y * w1.x + pi.z * w2.x + pi.w * w3.x;
            v.y = pi.x * w0.y + pi.y * w1.y + pi.z * w2.y + pi.w * w3.y;
            v.z = pi.x * w0.z + pi.y * w1.z + pi.z * w2.z + pi.w * w3.z;
            v.w = pi.x * w0.w + pi.y * w1.w + pi.z * w2.w + pi.w * w3.w;
            obase[(i * 4 + 0) * RLEN] = v.x;    // lanes: consecutive r -> coalesced
            obase[(i * 4 + 1) * RLEN] = v.y;
            obase[(i * 4 + 2) * RLEN] = v.z;
            obase[(i * 4 + 3) * RLEN] = v.w;
        }
    }
}

extern "C" void kernel_launch(void* const* d_in, const int* in_sizes, int n_in,
                              void* d_out, int out_size, void* d_ws, size_t ws_size,
                              hipStream_t stream) {
    const float* act   = (const float*)d_in[0];
    const float* poses = (const float*)d_in[1];
    const float* W     = (const float*)d_in[2];
    float* out = (float*)d_out;

    v8_kernel<<<1024, 256, 0, stream>>>(act, poses, W, out);
}